// Round 9
// baseline (206.457 us; speedup 1.0000x reference)
//
#include <hip/hip_runtime.h>

#pragma clang fp contract(off)

typedef unsigned long long u64;
typedef unsigned int u32;
typedef unsigned short u16;

#define BATCH 8
#define NA 131072
#define NSEL 6000
#define NT 24                 // 256-box tiles
#define TILE 256
#define NWORD (NT * 4)        // 96 64-bit words
#define NPAD (NT * TILE)      // 6144
#define CAND_CAP 8192
#define PROP 1000
#define SCAP 4096             // cross-tile entries cap per (batch, DEST tile)
#define LDSE 12288            // entries staged in LDS (u32 each)
#define CELLCAP 256           // boxes per 8x8 grid cell (mean ~94)
#define LARGECAP 1024         // "large" boxes per batch (dim > 1/8)
#define LTHR 0.125f
#define HB 16                 // hist blocks per batch (rows to sum)

// ---- workspace layout (bytes); NOTHING is pre-zeroed by the host ----
// histPB rows fully overwritten each launch; bfill/scnt/cellCnt zeroed by
// scan_kernel (ordered before their consumers by launch boundaries); tileT
// zeroed inside sortdecode_kernel; cand/sent/boxes bounds-guarded.
#define OFF_HISTPB   0            // BATCH*HB*256*4 = 131072
#define OFF_BFILL    131072       // 8224 -> pad 139328
#define OFF_SCNT     139328       // 768 -> pad 140160
#define OFF_CELLCNT  140160       // 2080 -> pad 142272
#define OFF_BSTG     142272       // BATCH*264*4 = 8448 -> pad 150784
#define OFF_TILET    150784       // 1572864 -> 1723648
#define OFF_CAND     1723648      // 524288 -> 2247936
#define OFF_BOXES    2247936      // 786432 -> 3034368
#define OFF_CELLLIST 3034368      // 262144 -> 3296512
#define OFF_LARGE    3296512      // 16384 -> 3312896
#define OFF_SENT     3312896      // 3145728 -> 6458624

__device__ __forceinline__ int bucket_of(u32 bits) {
  u32 hi = bits >> 16;
  if (hi >= 0x3E80u && hi < 0x3F80u) return (int)(hi - 0x3E80u);
  if (hi >= 0x3F80u && hi < 0x8000u) return 255;
  return -1;
}

// "RN32(inter / max(uni,1e-12)) > 0.7f" without fp32 divide, bit-exact:
// M=0x1.666667p-1 is the 0.7f/nextafter midpoint; RN32(t)>0.7f <=> t>=M;
// a/b>=M <=> a>=M*b, exact in fp64 (25-bit x 24-bit product).
__device__ __forceinline__ bool iou_gt(float4 A, float4 B, float areaA, float areaB) {
  float iy = fminf(A.z, B.z) - fmaxf(A.x, B.x);
  float ix = fminf(A.w, B.w) - fmaxf(A.y, B.y);
  float inter = fmaxf(iy, 0.0f) * fmaxf(ix, 0.0f);
  float uni = (areaA + areaB) - inter;
  float uc = fmaxf(uni, 1e-12f);
  return (double)inter >= 0x1.666667p-1 * (double)uc;
}

// Within-tile pairs -> dense bit matrix tileT[b][t][dst&255][(src&255)>>6].
// Cross-tile pairs -> u32 entry (src<<8)|(dst&255) in segment (b, dst_tile).
__device__ __forceinline__ void emit_pair(int b, int ra, int rb, u64* tileT,
                                          u32* sent, int* scnt) {
  int src = min(ra, rb), dst = max(ra, rb);
  int tsrc = src >> 8, tdst = dst >> 8;
  if (tsrc == tdst) {
    atomicOr(&tileT[(((size_t)b * NT + tdst) * TILE + (dst & 255)) * 4 + ((src >> 6) & 3)],
             1ULL << (src & 63));
  } else {
    int e = atomicAdd(&scnt[b * NT + tdst], 1);
    if (e < SCAP)
      sent[(size_t)(b * NT + tdst) * SCAP + e] = ((u32)src << 8) | (u32)(dst & 255);
  }
}

__device__ __forceinline__ u64 shfl_xor_u64(u64 v, int lanemask) {
  u32 lo = (u32)v, hi = (u32)(v >> 32);
  lo = (u32)__shfl_xor((int)lo, lanemask);
  hi = (u32)__shfl_xor((int)hi, lanemask);
  return ((u64)hi << 32) | (u64)lo;
}

__device__ __forceinline__ u64 valid_mask(int g) {
  int lo = g * 64;
  if (lo + 64 <= NSEL) return ~0ULL;
  if (lo >= NSEL) return 0ULL;
  return (1ULL << (NSEL - lo)) - 1ULL;
}

// Bitonic sort (descending) of NS = P*256 keys, 256 threads, P regs/thread.
// P=2 path (cnt<=512) produces s[0..512) identical to the P=4 path: the
// all-zero upper half of the 1024-wide sort never perturbs the lower 512.
template <int P>
__device__ __forceinline__ void bitonic_sort(u64* s, const u64* __restrict__ seg,
                                             int cnt, int tid) {
  const int NS = P * 256;
  u64 x[P];
#pragma unroll
  for (int p = 0; p < P; ++p) {
    int i = p * 256 + tid;
    x[p] = (i < cnt) ? seg[i] : 0ULL;
  }
  for (int k = 2; k <= 64; k <<= 1) {
    for (int j = k >> 1; j >= 1; j >>= 1) {
#pragma unroll
      for (int p = 0; p < P; ++p) {
        int i = p * 256 + tid;
        u64 pv = shfl_xor_u64(x[p], j);
        bool takemax = (((i & j) == 0) == ((i & k) == 0));
        u64 mx = x[p] > pv ? x[p] : pv;
        u64 mn = x[p] < pv ? x[p] : pv;
        x[p] = takemax ? mx : mn;
      }
    }
  }
#pragma unroll
  for (int p = 0; p < P; ++p) s[p * 256 + tid] = x[p];
  __syncthreads();
  for (int k = 128; k <= NS; k <<= 1) {
    for (int j = k >> 1; j >= 64; j >>= 1) {
      for (int q = tid; q < NS / 2; q += 256) {
        int i = ((q & ~(j - 1)) << 1) | (q & (j - 1));
        int ixj = i | j;
        u64 a = s[i], c = s[ixj];
        bool up = ((i & k) == 0);
        if (up ? (a < c) : (a > c)) { s[i] = c; s[ixj] = a; }
      }
      __syncthreads();
    }
#pragma unroll
    for (int p = 0; p < P; ++p) x[p] = s[p * 256 + tid];
    for (int j = 32; j >= 1; j >>= 1) {
#pragma unroll
      for (int p = 0; p < P; ++p) {
        int i = p * 256 + tid;
        u64 pv = shfl_xor_u64(x[p], j);
        bool takemax = (((i & j) == 0) == ((i & k) == 0));
        u64 mx = x[p] > pv ? x[p] : pv;
        u64 mn = x[p] < pv ? x[p] : pv;
        x[p] = takemax ? mx : mn;
      }
    }
    __syncthreads();
#pragma unroll
    for (int p = 0; p < P; ++p) s[p * 256 + tid] = x[p];
    __syncthreads();
  }
}

// K1: per-batch per-BLOCK 256-bucket histogram (non-atomic global write),
// HB=16 blocks per batch.
__global__ __launch_bounds__(256) void hist_kernel(const float* __restrict__ probs,
                                                   int* __restrict__ histPB) {
  int b = blockIdx.y;
  int bx = blockIdx.x;
  int tid = threadIdx.x;
  const float2* p2 = reinterpret_cast<const float2*>(probs);
  __shared__ int h[257];
  for (int i = tid; i < 257; i += 256) h[i] = 0;
  __syncthreads();
  int stride = gridDim.x * blockDim.x;
  for (int a = bx * blockDim.x + tid; a < NA; a += stride) {
    float sc = p2[(size_t)b * NA + a].y;
    int bk = bucket_of(__float_as_uint(sc));
    atomicAdd(&h[bk < 0 ? 256 : bk], 1);
  }
  __syncthreads();
  if (tid < 256) histPB[((size_t)b * HB + bx) * 256 + tid] = h[tid];
}

// K1b: ONE block per batch computes the descending-suffix scan of the summed
// histogram once, to global: bstG[b*264 + v] = sum_{u>v}, bstG[b*264+256] = tb.
// Removes the per-block 16-row sum + 8-round scan from gather/sortdecode
// (1024 blocks each). Also zeroes bfill/scnt/cellCnt (ordered before their
// consumers by launch boundaries).
__global__ __launch_bounds__(256) void scan_kernel(const int* __restrict__ histPB,
                                                   int* __restrict__ bstG,
                                                   int* __restrict__ bfill,
                                                   int* __restrict__ scnt,
                                                   int* __restrict__ cellCnt) {
  int b = blockIdx.x;
  int tid = threadIdx.x;
  __shared__ int h[256];
  __shared__ int suf[256];
  for (int i = tid; i < 257; i += 256) bfill[b * 257 + i] = 0;
  if (tid < NT) scnt[b * NT + tid] = 0;
  if (tid < 65) cellCnt[b * 65 + tid] = 0;
  if (tid == 0) bstG[b * 264 + 256] = 0;
  {
    const int* hp = histPB + (size_t)b * (HB * 256) + tid;
    int acc = 0;
#pragma unroll
    for (int k = 0; k < HB; ++k) acc += hp[k * 256];
    h[tid] = acc;
    suf[tid] = acc;
  }
  __syncthreads();
  for (int d = 1; d < 256; d <<= 1) {
    int add = (tid + d < 256) ? suf[tid + d] : 0;
    __syncthreads();
    suf[tid] += add;
    __syncthreads();
  }
  bstG[b * 264 + tid] = suf[tid] - h[tid];
  if (suf[tid] >= NSEL && (tid == 255 || suf[tid + 1] < NSEL))
    bstG[b * 264 + 256] = tid;
}

// K2: inline select + scatter candidate keys into bucket segments.
// bst table is precomputed (scan_kernel) -> one 1KB staged load per block.
__global__ __launch_bounds__(256) void gather_kernel(const float* __restrict__ probs,
                                                     const int* __restrict__ bstG,
                                                     int* __restrict__ bfill,
                                                     u64* __restrict__ cand) {
  int b = blockIdx.y;
  int tid = threadIdx.x;
  const float2* p2 = reinterpret_cast<const float2*>(probs);
  __shared__ int bst[256];
  __shared__ int tb_s;
  if (tid < 256) bst[tid] = bstG[b * 264 + tid];
  if (tid == 0) tb_s = bstG[b * 264 + 256];
  __syncthreads();
  int tb = tb_s;
  int stride = gridDim.x * blockDim.x;
  for (int a = blockIdx.x * blockDim.x + tid; a < NA; a += stride) {
    float sc = p2[(size_t)b * NA + a].y;
    u32 bits = __float_as_uint(sc);
    int bk = bucket_of(bits);
    if (bk >= tb) {
      int pos = bst[bk] + atomicAdd(&bfill[b * 257 + bk], 1);
      if (pos < CAND_CAP)
        cand[(size_t)b * CAND_CAP + pos] = ((u64)bits << 32) | (u64)(0xFFFFFFFFu - (u32)a);
    }
  }
}

// K3: per-(batch,bucket-slot) bitonic sort (adaptive 512/1024 wide) in LDS,
// then decode+clip+bin its own ranks directly from LDS.
// Also zeroes tileT for this batch. bst/tb are two scalar global loads.
__global__ __launch_bounds__(256) void sortdecode_kernel(const int* __restrict__ bstG,
                                                         const int* __restrict__ bfill,
                                                         const u64* __restrict__ cand,
                                                         const float* __restrict__ anchors,
                                                         const float* __restrict__ deltas,
                                                         float4* __restrict__ boxes,
                                                         int* __restrict__ cellCnt,
                                                         u16* __restrict__ cellList,
                                                         u16* __restrict__ largeList,
                                                         u64* __restrict__ tileT) {
  int b = blockIdx.y;
  int tid = threadIdx.x;
  for (int g = blockIdx.x * 256 + tid; g < NT * TILE * 4; g += 64 * 256)
    tileT[(size_t)b * (NT * TILE * 4) + g] = 0ULL;
  if (blockIdx.x == 0) {
    float4 z = {0.f, 0.f, 0.f, 0.f};
    for (int r = NSEL + tid; r < NPAD; r += 256) boxes[(size_t)b * NPAD + r] = z;
  }
  int tb = bstG[b * 264 + 256];
  int v = tb + blockIdx.x;
  if (v > 255) return;
  int start = bstG[b * 264 + v];
  if (start >= NSEL) return;  // ranks beyond NSEL are never consumed
  int cnt = min(min(bfill[b * 257 + v], 1024), CAND_CAP - start);
  if (cnt <= 0) return;
  const u64* seg = cand + (size_t)b * CAND_CAP + start;
  __shared__ u64 s[1024];
  if (cnt <= 512)
    bitonic_sort<2>(s, seg, cnt, tid);
  else
    bitonic_sort<4>(s, seg, cnt, tid);
  // decode + clip + bin ranks [start, start+cnt) ∩ [0, NSEL)
  for (int i = tid; i < cnt; i += 256) {
    int r = start + i;
    if (r >= NSEL) continue;
    u64 key = s[i];
    float4 o = {0.f, 0.f, 0.f, 0.f};
    u32 idx = 0xFFFFFFFFu - (u32)(key & 0xFFFFFFFFu);
    if (idx < NA) {
      float4 av = *reinterpret_cast<const float4*>(anchors + ((size_t)b * NA + idx) * 4);
      float4 dv = *reinterpret_cast<const float4*>(deltas + ((size_t)b * NA + idx) * 4);
      float y1 = av.x, x1 = av.y, y2 = av.z, x2 = av.w;
      float dy = dv.x * 0.1f, dx = dv.y * 0.1f;
      float dh = dv.z * 0.2f, dw = dv.w * 0.2f;
      float hh = y2 - y1, ww = x2 - x1;
      float cy = y1 + 0.5f * hh + dy * hh;
      float cx = x1 + 0.5f * ww + dx * ww;
      hh = hh * expf(dh);
      ww = ww * expf(dw);
      float ny1 = cy - 0.5f * hh, nx1 = cx - 0.5f * ww;
      float ny2 = ny1 + hh, nx2 = nx1 + ww;
      o.x = fminf(fmaxf(ny1, 0.f), 1.f);
      o.y = fminf(fmaxf(nx1, 0.f), 1.f);
      o.z = fminf(fmaxf(ny2, 0.f), 1.f);
      o.w = fminf(fmaxf(nx2, 0.f), 1.f);
    }
    boxes[(size_t)b * NPAD + r] = o;
    float bh = o.z - o.x, bw = o.w - o.y;
    if (bh > LTHR || bw > LTHR) {
      int pos = atomicAdd(&cellCnt[b * 65 + 64], 1);
      if (pos < LARGECAP) largeList[b * LARGECAP + pos] = (u16)r;
    } else {
      int gy = min(7, max(0, (int)((o.x + o.z) * 4.0f)));
      int gx = min(7, max(0, (int)((o.y + o.w) * 4.0f)));
      int cell = gy * 8 + gx;
      int pos = atomicAdd(&cellCnt[b * 65 + cell], 1);
      if (pos < CELLCAP) cellList[((size_t)b * 64 + cell) * CELLCAP + pos] = (u16)r;
    }
  }
}

// K4: blocks 0..63 = per-cell {self + boundary-band-filtered cross};
// blocks 64..127 = large-box window tests + large-large pairs.
__global__ __launch_bounds__(256) void pairs_kernel(const float4* __restrict__ boxes,
                                                    const u16* __restrict__ cellList,
                                                    const u16* __restrict__ largeList,
                                                    const int* __restrict__ cellCnt,
                                                    u64* __restrict__ tileT,
                                                    u32* __restrict__ sent,
                                                    int* __restrict__ scnt) {
  int b = blockIdx.y;
  int tid = threadIdx.x;
  if (blockIdx.x >= 64) {
    // ---- large path ----
    int lb = blockIdx.x - 64;  // 0..63
    int nL = min(cellCnt[b * 65 + 64], LARGECAP);
    if (nL == 0) return;
    for (int li = lb; li < nL; li += 64) {
      int L = largeList[b * LARGECAP + li];
      float4 Lb = boxes[(size_t)b * NPAD + L];
      float hL = Lb.z - Lb.x, wL = Lb.w - Lb.y;
      if (0.7f * hL >= 0.126f || 0.7f * wL >= 0.126f) continue;  // no small can match
      float La = hL * wL;
      float sLy = Lb.x + Lb.z, sLx = Lb.y + Lb.w;
      int gy0 = max(0, (int)((sLy - 0.08f) * 4.0f));
      int gy1 = min(7, (int)((sLy + 0.08f) * 4.0f));
      int gx0 = max(0, (int)((sLx - 0.08f) * 4.0f));
      int gx1 = min(7, (int)((sLx + 0.08f) * 4.0f));
      for (int gy = gy0; gy <= gy1; ++gy)
        for (int gx = gx0; gx <= gx1; ++gx) {
          int cc = gy * 8 + gx;
          int cnt = min(cellCnt[b * 65 + cc], CELLCAP);
          for (int i = tid; i < cnt; i += 256) {
            int r = cellList[((size_t)b * 64 + cc) * CELLCAP + i];
            float4 jb = boxes[(size_t)b * NPAD + r];
            float ja = (jb.z - jb.x) * (jb.w - jb.y);
            if (iou_gt(Lb, jb, La, ja)) emit_pair(b, L, r, tileT, sent, scnt);
          }
        }
    }
    // large-large, list-index i<j
    int s = 1;
    while ((1 << s) < nL) ++s;
    int tot = nL << s, m = (1 << s) - 1;
    int stride = 64 * 256;
    for (int t = lb * 256 + tid; t < tot; t += stride) {
      int i = t >> s, j = t & m;
      if (j >= nL || i >= j) continue;
      int Li = largeList[b * LARGECAP + i];
      int Lj = largeList[b * LARGECAP + j];
      float4 A = boxes[(size_t)b * NPAD + Li];
      float4 B = boxes[(size_t)b * NPAD + Lj];
      float aA = (A.z - A.x) * (A.w - A.y);
      float aB = (B.z - B.x) * (B.w - B.y);
      if (iou_gt(A, B, aA, aB)) emit_pair(b, Li, Lj, tileT, sent, scnt);
    }
    return;
  }
  // ---- cell path ----
  int c = blockIdx.x;
  int cy = c >> 3, cx = c & 7;
  int nA = min(cellCnt[b * 65 + c], CELLCAP);
  if (nA == 0) return;
  __shared__ float4 Ab[CELLCAP];
  __shared__ float Aa[CELLCAP];
  __shared__ float Asx[CELLCAP];  // x1+x2 = 2*center_x
  __shared__ float Asy[CELLCAP];  // y1+y2 = 2*center_y
  __shared__ u16 Ai[CELLCAP];
  __shared__ u16 fAi[CELLCAP];
  __shared__ float4 Bb[3 * CELLCAP];
  __shared__ float Ba[3 * CELLCAP];
  __shared__ u16 Bi[3 * CELLCAP];
  __shared__ int nfA_s, nfB_s;
  for (int i = tid; i < nA; i += 256) {
    int r = cellList[((size_t)b * 64 + c) * CELLCAP + i];
    float4 bx = boxes[(size_t)b * NPAD + r];
    Ab[i] = bx;
    Aa[i] = (bx.z - bx.x) * (bx.w - bx.y);
    Asy[i] = bx.x + bx.z;
    Asx[i] = bx.y + bx.w;
    Ai[i] = (u16)r;
  }
  __syncthreads();
  // self pairs: exact triangular enumeration
  {
    int totS = (nA * (nA - 1)) >> 1;
    for (int t = tid; t < totS; t += 256) {
      int i = (int)((1.0f + sqrtf(8.0f * (float)t + 1.0f)) * 0.5f);
      int tri = (i * (i - 1)) >> 1;
      if (t < tri) {
        --i;
        tri = (i * (i - 1)) >> 1;
      } else if (t >= tri + i) {
        tri += i;
        ++i;
      }
      int j = t - tri;
      if (iou_gt(Ab[i], Ab[j], Aa[i], Aa[j]))
        emit_pair(b, Ai[i], Ai[j], tileT, sent, scnt);
    }
  }
  // phase R: right neighbor, x boundary band
  if (cx < 7) {
    __syncthreads();
    if (tid == 0) { nfA_s = 0; nfB_s = 0; }
    __syncthreads();
    float XR2 = (float)(cx + 1) * 0.25f;
    for (int i = tid; i < nA; i += 256)
      if (Asx[i] > XR2 - 0.078f) fAi[atomicAdd(&nfA_s, 1)] = (u16)i;
    int nc = c + 1;
    int nN = min(cellCnt[b * 65 + nc], CELLCAP);
    for (int i = tid; i < nN; i += 256) {
      int r = cellList[((size_t)b * 64 + nc) * CELLCAP + i];
      float4 bx = boxes[(size_t)b * NPAD + r];
      if (bx.y + bx.w < XR2 + 0.078f) {
        int p = atomicAdd(&nfB_s, 1);
        Bb[p] = bx;
        Ba[p] = (bx.z - bx.x) * (bx.w - bx.y);
        Bi[p] = (u16)r;
      }
    }
    __syncthreads();
    int nfA = nfA_s, nfB = nfB_s;
    if (nfA && nfB) {
      int s = 1;
      while ((1 << s) < nfB) ++s;
      int tot = nfA << s, m = (1 << s) - 1;
      for (int t = tid; t < tot; t += 256) {
        int ii = fAi[t >> s], j = t & m;
        if (j < nfB && iou_gt(Ab[ii], Bb[j], Aa[ii], Ba[j]))
          emit_pair(b, Ai[ii], Bi[j], tileT, sent, scnt);
      }
    }
  }
  // phase D: three lower neighbors, y band (+x band for diagonals at staging)
  if (cy < 7) {
    __syncthreads();
    if (tid == 0) { nfA_s = 0; nfB_s = 0; }
    __syncthreads();
    float YB2 = (float)(cy + 1) * 0.25f;
    float XL2 = (float)cx * 0.25f;
    float XR2 = (float)(cx + 1) * 0.25f;
    for (int i = tid; i < nA; i += 256)
      if (Asy[i] > YB2 - 0.078f) fAi[atomicAdd(&nfA_s, 1)] = (u16)i;
    for (int k = 0; k < 3; ++k) {
      int nx = cx + k - 1;
      if (nx < 0 || nx > 7) continue;
      int nc = (cy + 1) * 8 + nx;
      int nN = min(cellCnt[b * 65 + nc], CELLCAP);
      for (int i = tid; i < nN; i += 256) {
        int r = cellList[((size_t)b * 64 + nc) * CELLCAP + i];
        float4 bx = boxes[(size_t)b * NPAD + r];
        float bsy = bx.x + bx.z, bsx = bx.y + bx.w;
        bool ok = bsy < YB2 + 0.078f;
        if (k == 0) ok = ok && (bsx > XL2 - 0.078f);
        if (k == 2) ok = ok && (bsx < XR2 + 0.078f);
        if (ok) {
          int p = atomicAdd(&nfB_s, 1);
          Bb[p] = bx;
          Ba[p] = (bx.z - bx.x) * (bx.w - bx.y);
          Bi[p] = (u16)r;
        }
      }
    }
    __syncthreads();
    int nfA = nfA_s, nfB = nfB_s;
    if (nfA && nfB) {
      int s = 1;
      while ((1 << s) < nfB) ++s;
      int tot = nfA << s, m = (1 << s) - 1;
      for (int t = tid; t < tot; t += 256) {
        int ii = fAi[t >> s], j = t & m;
        if (j < nfB && iou_gt(Ab[ii], Bb[j], Aa[ii], Ba[j]))
          emit_pair(b, Ai[ii], Bi[j], tileT, sent, scnt);
      }
    }
  }
}

// K5: greedy NMS, 256-box TILE scan. Cross-tile gather is BATCHED: read 4
// entries, issue 4 independent Kall loads, then 4 conditional rmb writes —
// one LDS latency per 256 entries instead of four.
__global__ __launch_bounds__(512) void nms_kernel(const u32* __restrict__ sent,
                                                  const int* __restrict__ scnt,
                                                  const u64* __restrict__ tileT,
                                                  const float4* __restrict__ boxes,
                                                  float4* __restrict__ out) {
  int b = blockIdx.x;
  int tid = threadIdx.x;
  int lane = tid & 63;
  int wv = tid >> 6;
  __shared__ u32 entS[LDSE];        // 49152 B
  __shared__ u32 rmb[TILE];         // 1024 B
  __shared__ u64 Kall[NWORD];       // 768 B
  __shared__ int cw[NT];
  __shared__ int prefix[NT + 1];
  __shared__ int baseT[NT];
  if (tid < NT) cw[tid] = min(scnt[b * NT + tid], SCAP);
  if (tid < TILE) rmb[tid] = 0u;
  if (tid < NWORD) Kall[tid] = 0ULL;
  {
    float4 z = {0.f, 0.f, 0.f, 0.f};
    for (int i = tid; i < PROP; i += 512) out[(size_t)b * PROP + i] = z;
  }
  __syncthreads();
  if (tid == 0) {
    int run = 0;
    for (int t = 0; t < NT; ++t) { prefix[t] = run; run += cw[t]; }
    prefix[NT] = run;
  }
  __syncthreads();
  for (int t = wv; t < NT; t += 8) {
    const u32* gb = sent + (size_t)(b * NT + t) * SCAP;
    int base = prefix[t], n = cw[t];
    for (int e = lane; e < n; e += 64) {
      int slot = base + e;
      if (slot < LDSE) entS[slot] = gb[e];
    }
  }
  __syncthreads();
  if (wv == 0) {
    const u64* tb0 = tileT + (size_t)b * (NT * TILE * 4);
    u64 mc[4][4], mn[4][4];
#pragma unroll
    for (int q = 0; q < 4; ++q)
#pragma unroll
      for (int j = 0; j < 4; ++j)
        mc[q][j] = tb0[(size_t)(q * 64 + lane) * 4 + j];
    int total = 0;
    for (int t = 0; t < NT; ++t) {
      if (t + 1 < NT) {
        const u64* nb = tb0 + (size_t)(t + 1) * (TILE * 4);
#pragma unroll
        for (int q = 0; q < 4; ++q)
#pragma unroll
          for (int j = 0; j < 4; ++j)
            mn[q][j] = nb[(size_t)(q * 64 + lane) * 4 + j];
      }
      // cross-tile gather, batched 4-wide
      {
        int n = cw[t], base = prefix[t];
        for (int e0 = 0; e0 < n; e0 += 256) {
          u32 ent[4];
          u64 kw[4];
          int ee[4];
#pragma unroll
          for (int u = 0; u < 4; ++u) {
            int e = e0 + u * 64 + lane;
            ee[u] = e;
            u32 vv = 0u;
            if (e < n) {
              int slot = base + e;
              vv = (slot < LDSE) ? entS[slot] : sent[(size_t)(b * NT + t) * SCAP + e];
            }
            ent[u] = vv;
          }
#pragma unroll
          for (int u = 0; u < 4; ++u) kw[u] = Kall[(int)(ent[u] >> 8) >> 6];
#pragma unroll
          for (int u = 0; u < 4; ++u) {
            int srcr = (int)(ent[u] >> 8);
            if (ee[u] < n && ((kw[u] >> (srcr & 63)) & 1ULL)) rmb[ent[u] & 255] = 1u;
          }
        }
      }
      u32 f0 = rmb[lane], f1 = rmb[64 + lane], f2 = rmb[128 + lane], f3 = rmb[192 + lane];
      rmb[lane] = 0u;
      rmb[64 + lane] = 0u;
      rmb[128 + lane] = 0u;
      rmb[192 + lane] = 0u;
      int gw = t * 4;
      u64 K0, K1, K2, K3;
      {
        bool alive0 = (f0 == 0u) && ((valid_mask(gw) >> lane) & 1ULL);
        u64 cm = mc[0][0];
        u64 K = __ballot(alive0);
        for (int it = 0; it < 70; ++it) {
          bool alive = alive0 && ((K & cm) == 0ULL);
          u64 Kn = __ballot(alive);
          if (Kn == K) break;
          K = Kn;
        }
        K0 = K;
      }
      {
        u64 pre = K0 & mc[1][0];
        bool alive0 = (f1 == 0u) && ((valid_mask(gw + 1) >> lane) & 1ULL) && (pre == 0ULL);
        u64 cm = mc[1][1];
        u64 K = __ballot(alive0);
        for (int it = 0; it < 70; ++it) {
          bool alive = alive0 && ((K & cm) == 0ULL);
          u64 Kn = __ballot(alive);
          if (Kn == K) break;
          K = Kn;
        }
        K1 = K;
      }
      {
        u64 pre = (K0 & mc[2][0]) | (K1 & mc[2][1]);
        bool alive0 = (f2 == 0u) && ((valid_mask(gw + 2) >> lane) & 1ULL) && (pre == 0ULL);
        u64 cm = mc[2][2];
        u64 K = __ballot(alive0);
        for (int it = 0; it < 70; ++it) {
          bool alive = alive0 && ((K & cm) == 0ULL);
          u64 Kn = __ballot(alive);
          if (Kn == K) break;
          K = Kn;
        }
        K2 = K;
      }
      {
        u64 pre = (K0 & mc[3][0]) | (K1 & mc[3][1]) | (K2 & mc[3][2]);
        bool alive0 = (f3 == 0u) && ((valid_mask(gw + 3) >> lane) & 1ULL) && (pre == 0ULL);
        u64 cm = mc[3][3];
        u64 K = __ballot(alive0);
        for (int it = 0; it < 70; ++it) {
          bool alive = alive0 && ((K & cm) == 0ULL);
          u64 Kn = __ballot(alive);
          if (Kn == K) break;
          K = Kn;
        }
        K3 = K;
      }
      if (lane == 0) {
        Kall[gw] = K0;
        Kall[gw + 1] = K1;
        Kall[gw + 2] = K2;
        Kall[gw + 3] = K3;
        baseT[t] = total;
      }
      total += __popcll(K0) + __popcll(K1) + __popcll(K2) + __popcll(K3);
#pragma unroll
      for (int q = 0; q < 4; ++q)
#pragma unroll
        for (int j = 0; j < 4; ++j)
          mc[q][j] = mn[q][j];
    }
  }
  __syncthreads();
  for (int i = tid; i < NSEL; i += 512) {
    int g = i >> 6, bb = i & 63;
    u64 K = Kall[g];
    if ((K >> bb) & 1ULL) {
      int t = i >> 8;
      int rank = baseT[t];
      for (int q = t * 4; q < g; ++q) rank += __popcll(Kall[q]);
      rank += __popcll(K & ((1ULL << bb) - 1ULL));
      if (rank < PROP) out[(size_t)b * PROP + rank] = boxes[(size_t)b * NPAD + i];
    }
  }
}

extern "C" void kernel_launch(void* const* d_in, const int* in_sizes, int n_in,
                              void* d_out, int out_size, void* d_ws, size_t ws_size,
                              hipStream_t stream) {
  const float* probs = (const float*)d_in[0];    // (8,131072,2)
  const float* deltas = (const float*)d_in[1];   // (8,131072,4)
  const float* anchors = (const float*)d_in[2];  // (8,131072,4)
  char* ws = (char*)d_ws;
  int* histPB = (int*)(ws + OFF_HISTPB);
  int* bfill = (int*)(ws + OFF_BFILL);
  int* scnt = (int*)(ws + OFF_SCNT);
  int* cellCnt = (int*)(ws + OFF_CELLCNT);
  int* bstG = (int*)(ws + OFF_BSTG);
  u64* tileT = (u64*)(ws + OFF_TILET);
  u64* cand = (u64*)(ws + OFF_CAND);
  float4* boxes = (float4*)(ws + OFF_BOXES);
  u16* cellList = (u16*)(ws + OFF_CELLLIST);
  u16* largeList = (u16*)(ws + OFF_LARGE);
  u32* sent = (u32*)(ws + OFF_SENT);

  hist_kernel<<<dim3(HB, BATCH), 256, 0, stream>>>(probs, histPB);
  scan_kernel<<<BATCH, 256, 0, stream>>>(histPB, bstG, bfill, scnt, cellCnt);
  gather_kernel<<<dim3(64, BATCH), 256, 0, stream>>>(probs, bstG, bfill, cand);
  sortdecode_kernel<<<dim3(64, BATCH), 256, 0, stream>>>(bstG, bfill, cand, anchors,
                                                         deltas, boxes, cellCnt,
                                                         cellList, largeList, tileT);
  pairs_kernel<<<dim3(128, BATCH), 256, 0, stream>>>(boxes, cellList, largeList,
                                                     cellCnt, tileT, sent, scnt);
  nms_kernel<<<BATCH, 512, 0, stream>>>(sent, scnt, tileT, boxes, (float4*)d_out);
}

// Round 10
// 203.612 us; speedup vs baseline: 1.0140x; 1.0140x over previous
//
#include <hip/hip_runtime.h>

#pragma clang fp contract(off)

typedef unsigned long long u64;
typedef unsigned int u32;
typedef unsigned short u16;

#define BATCH 8
#define NA 131072
#define NSEL 6000
#define NT 24                 // 256-box tiles
#define TILE 256
#define NWORD (NT * 4)        // 96 64-bit words
#define NPAD (NT * TILE)      // 6144
#define CAND_CAP 8192
#define PROP 1000
#define SCAP 4096             // cross-tile entries cap per (batch, DEST tile)
#define LDSE 12288            // entries staged in LDS (u32 each)
#define CELLCAP 256           // boxes per 8x8 grid cell (mean ~94)
#define LARGECAP 1024         // "large" boxes per batch (dim > 1/8)
#define LTHR 0.125f
#define HB 16                 // hist blocks per batch (rows to sum)

// ---- workspace layout (bytes); NOTHING is pre-zeroed by the host ----
// histPB rows fully overwritten each launch; bfill/scnt/cellCnt zeroed by
// hist_kernel block 0 of each batch (ordered by launch boundary); tileT
// zeroed inside sortdecode_kernel; cand/sent/boxes bounds-guarded.
#define OFF_HISTPB   0            // BATCH*HB*256*4 = 131072
#define OFF_BFILL    131072       // 8224 -> pad 139328
#define OFF_SCNT     139328       // 768 -> pad 140160
#define OFF_CELLCNT  140160       // 2080 -> pad 142272
#define OFF_TILET    142272       // 1572864 -> 1715136
#define OFF_CAND     1715136      // 524288 -> 2239424
#define OFF_BOXES    2239424      // 786432 -> 3025856
#define OFF_CELLLIST 3025856      // 262144 -> 3288000
#define OFF_LARGE    3288000      // 16384 -> 3304384
#define OFF_SENT     3304384      // 3145728 -> 6450112

__device__ __forceinline__ int bucket_of(u32 bits) {
  u32 hi = bits >> 16;
  if (hi >= 0x3E80u && hi < 0x3F80u) return (int)(hi - 0x3E80u);
  if (hi >= 0x3F80u && hi < 0x8000u) return 255;
  return -1;
}

// "RN32(inter / max(uni,1e-12)) > 0.7f" without fp32 divide, bit-exact:
// M=0x1.666667p-1 is the 0.7f/nextafter midpoint; RN32(t)>0.7f <=> t>=M;
// a/b>=M <=> a>=M*b, exact in fp64 (25-bit x 24-bit product).
__device__ __forceinline__ bool iou_gt(float4 A, float4 B, float areaA, float areaB) {
  float iy = fminf(A.z, B.z) - fmaxf(A.x, B.x);
  float ix = fminf(A.w, B.w) - fmaxf(A.y, B.y);
  float inter = fmaxf(iy, 0.0f) * fmaxf(ix, 0.0f);
  float uni = (areaA + areaB) - inter;
  float uc = fmaxf(uni, 1e-12f);
  return (double)inter >= 0x1.666667p-1 * (double)uc;
}

// Within-tile pairs -> dense bit matrix tileT[b][t][dst&255][(src&255)>>6].
// Cross-tile pairs -> u32 entry (src<<8)|(dst&255) in segment (b, dst_tile).
__device__ __forceinline__ void emit_pair(int b, int ra, int rb, u64* tileT,
                                          u32* sent, int* scnt) {
  int src = min(ra, rb), dst = max(ra, rb);
  int tsrc = src >> 8, tdst = dst >> 8;
  if (tsrc == tdst) {
    atomicOr(&tileT[(((size_t)b * NT + tdst) * TILE + (dst & 255)) * 4 + ((src >> 6) & 3)],
             1ULL << (src & 63));
  } else {
    int e = atomicAdd(&scnt[b * NT + tdst], 1);
    if (e < SCAP)
      sent[(size_t)(b * NT + tdst) * SCAP + e] = ((u32)src << 8) | (u32)(dst & 255);
  }
}

__device__ __forceinline__ u64 shfl_xor_u64(u64 v, int lanemask) {
  u32 lo = (u32)v, hi = (u32)(v >> 32);
  lo = (u32)__shfl_xor((int)lo, lanemask);
  hi = (u32)__shfl_xor((int)hi, lanemask);
  return ((u64)hi << 32) | (u64)lo;
}

__device__ __forceinline__ u64 valid_mask(int g) {
  int lo = g * 64;
  if (lo + 64 <= NSEL) return ~0ULL;
  if (lo >= NSEL) return 0ULL;
  return (1ULL << (NSEL - lo)) - 1ULL;
}

// PARALLEL descending-suffix scan of the 16-row per-block histogram.
// h[v] = sum of rows; suf[v] = sum_{u>=v} h[u] (Hillis-Steele, 8 rounds);
// bst[v] = suf[v]-h[v] = sum_{u>v}; tb = largest v with suf[v] >= NSEL.
// Identical integer arithmetic to the serial loop (verified rounds 5/6)
// -> bit-identical tb/bst in every block.
__device__ __forceinline__ void prefix_from_hist(const int* __restrict__ histPB,
                                                 int b, int* h, int* suf,
                                                 int* bst, int* tb_s) {
  int tid = threadIdx.x;
  {
    const int* hp = histPB + (size_t)b * (HB * 256) + tid;
    int acc = 0;
#pragma unroll
    for (int k = 0; k < HB; ++k) acc += hp[k * 256];
    h[tid] = acc;
    suf[tid] = acc;
  }
  if (tid == 0) *tb_s = 0;
  __syncthreads();
  for (int d = 1; d < 256; d <<= 1) {
    int add = (tid + d < 256) ? suf[tid + d] : 0;
    __syncthreads();
    suf[tid] += add;
    __syncthreads();
  }
  bst[tid] = suf[tid] - h[tid];
  if (suf[tid] >= NSEL && (tid == 255 || suf[tid + 1] < NSEL)) *tb_s = tid;
  __syncthreads();
}

// Bitonic sort (descending) of NS = P*256 keys, 256 threads, P regs/thread.
// P=2 path (cnt<=512) produces s[0..512) identical to the P=4 path: the
// all-zero upper half of the 1024-wide sort never perturbs the lower 512
// (final merge compares real keys against zeros and never swaps).
template <int P>
__device__ __forceinline__ void bitonic_sort(u64* s, const u64* __restrict__ seg,
                                             int cnt, int tid) {
  const int NS = P * 256;
  u64 x[P];
#pragma unroll
  for (int p = 0; p < P; ++p) {
    int i = p * 256 + tid;
    x[p] = (i < cnt) ? seg[i] : 0ULL;
  }
  for (int k = 2; k <= 64; k <<= 1) {
    for (int j = k >> 1; j >= 1; j >>= 1) {
#pragma unroll
      for (int p = 0; p < P; ++p) {
        int i = p * 256 + tid;
        u64 pv = shfl_xor_u64(x[p], j);
        bool takemax = (((i & j) == 0) == ((i & k) == 0));
        u64 mx = x[p] > pv ? x[p] : pv;
        u64 mn = x[p] < pv ? x[p] : pv;
        x[p] = takemax ? mx : mn;
      }
    }
  }
#pragma unroll
  for (int p = 0; p < P; ++p) s[p * 256 + tid] = x[p];
  __syncthreads();
  for (int k = 128; k <= NS; k <<= 1) {
    for (int j = k >> 1; j >= 64; j >>= 1) {
      for (int q = tid; q < NS / 2; q += 256) {
        int i = ((q & ~(j - 1)) << 1) | (q & (j - 1));
        int ixj = i | j;
        u64 a = s[i], c = s[ixj];
        bool up = ((i & k) == 0);
        if (up ? (a < c) : (a > c)) { s[i] = c; s[ixj] = a; }
      }
      __syncthreads();
    }
#pragma unroll
    for (int p = 0; p < P; ++p) x[p] = s[p * 256 + tid];
    for (int j = 32; j >= 1; j >>= 1) {
#pragma unroll
      for (int p = 0; p < P; ++p) {
        int i = p * 256 + tid;
        u64 pv = shfl_xor_u64(x[p], j);
        bool takemax = (((i & j) == 0) == ((i & k) == 0));
        u64 mx = x[p] > pv ? x[p] : pv;
        u64 mn = x[p] < pv ? x[p] : pv;
        x[p] = takemax ? mx : mn;
      }
    }
    __syncthreads();
#pragma unroll
    for (int p = 0; p < P; ++p) s[p * 256 + tid] = x[p];
    __syncthreads();
  }
}

// K1: per-batch per-BLOCK 256-bucket histogram (non-atomic global write),
// HB=16 blocks per batch. Block 0 also zeroes bfill/scnt/cellCnt.
__global__ __launch_bounds__(256) void hist_kernel(const float* __restrict__ probs,
                                                   int* __restrict__ histPB,
                                                   int* __restrict__ bfill,
                                                   int* __restrict__ scnt,
                                                   int* __restrict__ cellCnt) {
  int b = blockIdx.y;
  int bx = blockIdx.x;
  int tid = threadIdx.x;
  const float2* p2 = reinterpret_cast<const float2*>(probs);
  __shared__ int h[257];
  for (int i = tid; i < 257; i += 256) h[i] = 0;
  if (bx == 0) {
    if (tid < 257) bfill[b * 257 + tid] = 0;
    if (tid < NT) scnt[b * NT + tid] = 0;
    if (tid < 65) cellCnt[b * 65 + tid] = 0;
  }
  __syncthreads();
  int stride = gridDim.x * blockDim.x;
  for (int a = bx * blockDim.x + tid; a < NA; a += stride) {
    float sc = p2[(size_t)b * NA + a].y;
    int bk = bucket_of(__float_as_uint(sc));
    atomicAdd(&h[bk < 0 ? 256 : bk], 1);
  }
  __syncthreads();
  if (tid < 256) histPB[((size_t)b * HB + bx) * 256 + tid] = h[tid];
}

// K2: inline select + scatter candidate keys into bucket segments
__global__ __launch_bounds__(256) void gather_kernel(const float* __restrict__ probs,
                                                     const int* __restrict__ histPB,
                                                     int* __restrict__ bfill,
                                                     u64* __restrict__ cand) {
  int b = blockIdx.y;
  const float2* p2 = reinterpret_cast<const float2*>(probs);
  __shared__ int h[256];
  __shared__ int suf[256];
  __shared__ int bst[256];
  __shared__ int tb_s;
  prefix_from_hist(histPB, b, h, suf, bst, &tb_s);
  int tb = tb_s;
  int stride = gridDim.x * blockDim.x;
  for (int a = blockIdx.x * blockDim.x + threadIdx.x; a < NA; a += stride) {
    float sc = p2[(size_t)b * NA + a].y;
    u32 bits = __float_as_uint(sc);
    int bk = bucket_of(bits);
    if (bk >= tb) {
      int pos = bst[bk] + atomicAdd(&bfill[b * 257 + bk], 1);
      if (pos < CAND_CAP)
        cand[(size_t)b * CAND_CAP + pos] = ((u64)bits << 32) | (u64)(0xFFFFFFFFu - (u32)a);
    }
  }
}

// K3: per-(batch,bucket-slot) bitonic sort (adaptive 512/1024 wide) in LDS,
// then decode+clip+bin its own ranks directly from LDS.
// Also zeroes tileT for this batch (runs before pairs_kernel).
__global__ __launch_bounds__(256) void sortdecode_kernel(const int* __restrict__ histPB,
                                                         const int* __restrict__ bfill,
                                                         const u64* __restrict__ cand,
                                                         const float* __restrict__ anchors,
                                                         const float* __restrict__ deltas,
                                                         float4* __restrict__ boxes,
                                                         int* __restrict__ cellCnt,
                                                         u16* __restrict__ cellList,
                                                         u16* __restrict__ largeList,
                                                         u64* __restrict__ tileT) {
  int b = blockIdx.y;
  int tid = threadIdx.x;
  for (int g = blockIdx.x * 256 + tid; g < NT * TILE * 4; g += 64 * 256)
    tileT[(size_t)b * (NT * TILE * 4) + g] = 0ULL;
  __shared__ int h[256];
  __shared__ int suf[256];
  __shared__ int bst[256];
  __shared__ int tb_s;
  prefix_from_hist(histPB, b, h, suf, bst, &tb_s);
  if (blockIdx.x == 0) {
    float4 z = {0.f, 0.f, 0.f, 0.f};
    for (int r = NSEL + tid; r < NPAD; r += 256) boxes[(size_t)b * NPAD + r] = z;
  }
  int v = tb_s + blockIdx.x;
  if (v > 255) return;
  int start = bst[v];
  if (start >= NSEL) return;  // ranks beyond NSEL are never consumed
  int cnt = min(min(bfill[b * 257 + v], 1024), CAND_CAP - start);
  if (cnt <= 0) return;
  const u64* seg = cand + (size_t)b * CAND_CAP + start;
  __shared__ u64 s[1024];
  if (cnt <= 512)
    bitonic_sort<2>(s, seg, cnt, tid);
  else
    bitonic_sort<4>(s, seg, cnt, tid);
  // decode + clip + bin ranks [start, start+cnt) ∩ [0, NSEL)
  for (int i = tid; i < cnt; i += 256) {
    int r = start + i;
    if (r >= NSEL) continue;
    u64 key = s[i];
    float4 o = {0.f, 0.f, 0.f, 0.f};
    u32 idx = 0xFFFFFFFFu - (u32)(key & 0xFFFFFFFFu);
    if (idx < NA) {
      float4 av = *reinterpret_cast<const float4*>(anchors + ((size_t)b * NA + idx) * 4);
      float4 dv = *reinterpret_cast<const float4*>(deltas + ((size_t)b * NA + idx) * 4);
      float y1 = av.x, x1 = av.y, y2 = av.z, x2 = av.w;
      float dy = dv.x * 0.1f, dx = dv.y * 0.1f;
      float dh = dv.z * 0.2f, dw = dv.w * 0.2f;
      float hh = y2 - y1, ww = x2 - x1;
      float cy = y1 + 0.5f * hh + dy * hh;
      float cx = x1 + 0.5f * ww + dx * ww;
      hh = hh * expf(dh);
      ww = ww * expf(dw);
      float ny1 = cy - 0.5f * hh, nx1 = cx - 0.5f * ww;
      float ny2 = ny1 + hh, nx2 = nx1 + ww;
      o.x = fminf(fmaxf(ny1, 0.f), 1.f);
      o.y = fminf(fmaxf(nx1, 0.f), 1.f);
      o.z = fminf(fmaxf(ny2, 0.f), 1.f);
      o.w = fminf(fmaxf(nx2, 0.f), 1.f);
    }
    boxes[(size_t)b * NPAD + r] = o;
    float bh = o.z - o.x, bw = o.w - o.y;
    if (bh > LTHR || bw > LTHR) {
      int pos = atomicAdd(&cellCnt[b * 65 + 64], 1);
      if (pos < LARGECAP) largeList[b * LARGECAP + pos] = (u16)r;
    } else {
      int gy = min(7, max(0, (int)((o.x + o.z) * 4.0f)));
      int gx = min(7, max(0, (int)((o.y + o.w) * 4.0f)));
      int cell = gy * 8 + gx;
      int pos = atomicAdd(&cellCnt[b * 65 + cell], 1);
      if (pos < CELLCAP) cellList[((size_t)b * 64 + cell) * CELLCAP + pos] = (u16)r;
    }
  }
}

// K4: blocks 0..63 = per-cell {self + boundary-band-filtered cross};
// blocks 64..127 = large-box window tests + large-large pairs.
__global__ __launch_bounds__(256) void pairs_kernel(const float4* __restrict__ boxes,
                                                    const u16* __restrict__ cellList,
                                                    const u16* __restrict__ largeList,
                                                    const int* __restrict__ cellCnt,
                                                    u64* __restrict__ tileT,
                                                    u32* __restrict__ sent,
                                                    int* __restrict__ scnt) {
  int b = blockIdx.y;
  int tid = threadIdx.x;
  if (blockIdx.x >= 64) {
    // ---- large path ----
    int lb = blockIdx.x - 64;  // 0..63
    int nL = min(cellCnt[b * 65 + 64], LARGECAP);
    if (nL == 0) return;
    for (int li = lb; li < nL; li += 64) {
      int L = largeList[b * LARGECAP + li];
      float4 Lb = boxes[(size_t)b * NPAD + L];
      float hL = Lb.z - Lb.x, wL = Lb.w - Lb.y;
      if (0.7f * hL >= 0.126f || 0.7f * wL >= 0.126f) continue;  // no small can match
      float La = hL * wL;
      float sLy = Lb.x + Lb.z, sLx = Lb.y + Lb.w;
      int gy0 = max(0, (int)((sLy - 0.08f) * 4.0f));
      int gy1 = min(7, (int)((sLy + 0.08f) * 4.0f));
      int gx0 = max(0, (int)((sLx - 0.08f) * 4.0f));
      int gx1 = min(7, (int)((sLx + 0.08f) * 4.0f));
      for (int gy = gy0; gy <= gy1; ++gy)
        for (int gx = gx0; gx <= gx1; ++gx) {
          int cc = gy * 8 + gx;
          int cnt = min(cellCnt[b * 65 + cc], CELLCAP);
          for (int i = tid; i < cnt; i += 256) {
            int r = cellList[((size_t)b * 64 + cc) * CELLCAP + i];
            float4 jb = boxes[(size_t)b * NPAD + r];
            float ja = (jb.z - jb.x) * (jb.w - jb.y);
            if (iou_gt(Lb, jb, La, ja)) emit_pair(b, L, r, tileT, sent, scnt);
          }
        }
    }
    // large-large, list-index i<j
    int s = 1;
    while ((1 << s) < nL) ++s;
    int tot = nL << s, m = (1 << s) - 1;
    int stride = 64 * 256;
    for (int t = lb * 256 + tid; t < tot; t += stride) {
      int i = t >> s, j = t & m;
      if (j >= nL || i >= j) continue;
      int Li = largeList[b * LARGECAP + i];
      int Lj = largeList[b * LARGECAP + j];
      float4 A = boxes[(size_t)b * NPAD + Li];
      float4 B = boxes[(size_t)b * NPAD + Lj];
      float aA = (A.z - A.x) * (A.w - A.y);
      float aB = (B.z - B.x) * (B.w - B.y);
      if (iou_gt(A, B, aA, aB)) emit_pair(b, Li, Lj, tileT, sent, scnt);
    }
    return;
  }
  // ---- cell path ----
  int c = blockIdx.x;
  int cy = c >> 3, cx = c & 7;
  int nA = min(cellCnt[b * 65 + c], CELLCAP);
  if (nA == 0) return;
  __shared__ float4 Ab[CELLCAP];
  __shared__ float Aa[CELLCAP];
  __shared__ float Asx[CELLCAP];  // x1+x2 = 2*center_x
  __shared__ float Asy[CELLCAP];  // y1+y2 = 2*center_y
  __shared__ u16 Ai[CELLCAP];
  __shared__ u16 fAi[CELLCAP];
  __shared__ float4 Bb[3 * CELLCAP];
  __shared__ float Ba[3 * CELLCAP];
  __shared__ u16 Bi[3 * CELLCAP];
  __shared__ int nfA_s, nfB_s;
  for (int i = tid; i < nA; i += 256) {
    int r = cellList[((size_t)b * 64 + c) * CELLCAP + i];
    float4 bx = boxes[(size_t)b * NPAD + r];
    Ab[i] = bx;
    Aa[i] = (bx.z - bx.x) * (bx.w - bx.y);
    Asy[i] = bx.x + bx.z;
    Asx[i] = bx.y + bx.w;
    Ai[i] = (u16)r;
  }
  __syncthreads();
  // self pairs: exact triangular enumeration
  {
    int totS = (nA * (nA - 1)) >> 1;
    for (int t = tid; t < totS; t += 256) {
      int i = (int)((1.0f + sqrtf(8.0f * (float)t + 1.0f)) * 0.5f);
      int tri = (i * (i - 1)) >> 1;
      if (t < tri) {
        --i;
        tri = (i * (i - 1)) >> 1;
      } else if (t >= tri + i) {
        tri += i;
        ++i;
      }
      int j = t - tri;
      if (iou_gt(Ab[i], Ab[j], Aa[i], Aa[j]))
        emit_pair(b, Ai[i], Ai[j], tileT, sent, scnt);
    }
  }
  // phase R: right neighbor, x boundary band
  if (cx < 7) {
    __syncthreads();
    if (tid == 0) { nfA_s = 0; nfB_s = 0; }
    __syncthreads();
    float XR2 = (float)(cx + 1) * 0.25f;
    for (int i = tid; i < nA; i += 256)
      if (Asx[i] > XR2 - 0.078f) fAi[atomicAdd(&nfA_s, 1)] = (u16)i;
    int nc = c + 1;
    int nN = min(cellCnt[b * 65 + nc], CELLCAP);
    for (int i = tid; i < nN; i += 256) {
      int r = cellList[((size_t)b * 64 + nc) * CELLCAP + i];
      float4 bx = boxes[(size_t)b * NPAD + r];
      if (bx.y + bx.w < XR2 + 0.078f) {
        int p = atomicAdd(&nfB_s, 1);
        Bb[p] = bx;
        Ba[p] = (bx.z - bx.x) * (bx.w - bx.y);
        Bi[p] = (u16)r;
      }
    }
    __syncthreads();
    int nfA = nfA_s, nfB = nfB_s;
    if (nfA && nfB) {
      int s = 1;
      while ((1 << s) < nfB) ++s;
      int tot = nfA << s, m = (1 << s) - 1;
      for (int t = tid; t < tot; t += 256) {
        int ii = fAi[t >> s], j = t & m;
        if (j < nfB && iou_gt(Ab[ii], Bb[j], Aa[ii], Ba[j]))
          emit_pair(b, Ai[ii], Bi[j], tileT, sent, scnt);
      }
    }
  }
  // phase D: three lower neighbors, y band (+x band for diagonals at staging)
  if (cy < 7) {
    __syncthreads();
    if (tid == 0) { nfA_s = 0; nfB_s = 0; }
    __syncthreads();
    float YB2 = (float)(cy + 1) * 0.25f;
    float XL2 = (float)cx * 0.25f;
    float XR2 = (float)(cx + 1) * 0.25f;
    for (int i = tid; i < nA; i += 256)
      if (Asy[i] > YB2 - 0.078f) fAi[atomicAdd(&nfA_s, 1)] = (u16)i;
    for (int k = 0; k < 3; ++k) {
      int nx = cx + k - 1;
      if (nx < 0 || nx > 7) continue;
      int nc = (cy + 1) * 8 + nx;
      int nN = min(cellCnt[b * 65 + nc], CELLCAP);
      for (int i = tid; i < nN; i += 256) {
        int r = cellList[((size_t)b * 64 + nc) * CELLCAP + i];
        float4 bx = boxes[(size_t)b * NPAD + r];
        float bsy = bx.x + bx.z, bsx = bx.y + bx.w;
        bool ok = bsy < YB2 + 0.078f;
        if (k == 0) ok = ok && (bsx > XL2 - 0.078f);
        if (k == 2) ok = ok && (bsx < XR2 + 0.078f);
        if (ok) {
          int p = atomicAdd(&nfB_s, 1);
          Bb[p] = bx;
          Ba[p] = (bx.z - bx.x) * (bx.w - bx.y);
          Bi[p] = (u16)r;
        }
      }
    }
    __syncthreads();
    int nfA = nfA_s, nfB = nfB_s;
    if (nfA && nfB) {
      int s = 1;
      while ((1 << s) < nfB) ++s;
      int tot = nfA << s, m = (1 << s) - 1;
      for (int t = tid; t < tot; t += 256) {
        int ii = fAi[t >> s], j = t & m;
        if (j < nfB && iou_gt(Ab[ii], Bb[j], Aa[ii], Ba[j]))
          emit_pair(b, Ai[ii], Bi[j], tileT, sent, scnt);
      }
    }
  }
}

// K5: greedy NMS, 256-box TILE scan (round-4 verified version).
__global__ __launch_bounds__(512) void nms_kernel(const u32* __restrict__ sent,
                                                  const int* __restrict__ scnt,
                                                  const u64* __restrict__ tileT,
                                                  const float4* __restrict__ boxes,
                                                  float4* __restrict__ out) {
  int b = blockIdx.x;
  int tid = threadIdx.x;
  int lane = tid & 63;
  int wv = tid >> 6;
  __shared__ u32 entS[LDSE];        // 49152 B
  __shared__ u32 rmb[TILE];         // 1024 B
  __shared__ u64 Kall[NWORD];       // 768 B
  __shared__ int cw[NT];
  __shared__ int prefix[NT + 1];
  __shared__ int baseT[NT];
  if (tid < NT) cw[tid] = min(scnt[b * NT + tid], SCAP);
  if (tid < TILE) rmb[tid] = 0u;
  if (tid < NWORD) Kall[tid] = 0ULL;
  {
    float4 z = {0.f, 0.f, 0.f, 0.f};
    for (int i = tid; i < PROP; i += 512) out[(size_t)b * PROP + i] = z;
  }
  __syncthreads();
  if (tid == 0) {
    int run = 0;
    for (int t = 0; t < NT; ++t) { prefix[t] = run; run += cw[t]; }
    prefix[NT] = run;
  }
  __syncthreads();
  for (int t = wv; t < NT; t += 8) {
    const u32* gb = sent + (size_t)(b * NT + t) * SCAP;
    int base = prefix[t], n = cw[t];
    for (int e = lane; e < n; e += 64) {
      int slot = base + e;
      if (slot < LDSE) entS[slot] = gb[e];
    }
  }
  __syncthreads();
  if (wv == 0) {
    const u64* tb0 = tileT + (size_t)b * (NT * TILE * 4);
    u64 mc[4][4], mn[4][4];
#pragma unroll
    for (int q = 0; q < 4; ++q)
#pragma unroll
      for (int j = 0; j < 4; ++j)
        mc[q][j] = tb0[(size_t)(q * 64 + lane) * 4 + j];
    int total = 0;
    for (int t = 0; t < NT; ++t) {
      if (t + 1 < NT) {
        const u64* nb = tb0 + (size_t)(t + 1) * (TILE * 4);
#pragma unroll
        for (int q = 0; q < 4; ++q)
#pragma unroll
          for (int j = 0; j < 4; ++j)
            mn[q][j] = nb[(size_t)(q * 64 + lane) * 4 + j];
      }
      {
        int n = cw[t], base = prefix[t];
        for (int e = lane; e < n; e += 64) {
          int slot = base + e;
          u32 ent = (slot < LDSE) ? entS[slot] : sent[(size_t)(b * NT + t) * SCAP + e];
          int srcr = (int)(ent >> 8);
          if ((Kall[srcr >> 6] >> (srcr & 63)) & 1ULL) rmb[ent & 255] = 1u;
        }
      }
      u32 f0 = rmb[lane], f1 = rmb[64 + lane], f2 = rmb[128 + lane], f3 = rmb[192 + lane];
      rmb[lane] = 0u;
      rmb[64 + lane] = 0u;
      rmb[128 + lane] = 0u;
      rmb[192 + lane] = 0u;
      int gw = t * 4;
      u64 K0, K1, K2, K3;
      {
        bool alive0 = (f0 == 0u) && ((valid_mask(gw) >> lane) & 1ULL);
        u64 cm = mc[0][0];
        u64 K = __ballot(alive0);
        for (int it = 0; it < 70; ++it) {
          bool alive = alive0 && ((K & cm) == 0ULL);
          u64 Kn = __ballot(alive);
          if (Kn == K) break;
          K = Kn;
        }
        K0 = K;
      }
      {
        u64 pre = K0 & mc[1][0];
        bool alive0 = (f1 == 0u) && ((valid_mask(gw + 1) >> lane) & 1ULL) && (pre == 0ULL);
        u64 cm = mc[1][1];
        u64 K = __ballot(alive0);
        for (int it = 0; it < 70; ++it) {
          bool alive = alive0 && ((K & cm) == 0ULL);
          u64 Kn = __ballot(alive);
          if (Kn == K) break;
          K = Kn;
        }
        K1 = K;
      }
      {
        u64 pre = (K0 & mc[2][0]) | (K1 & mc[2][1]);
        bool alive0 = (f2 == 0u) && ((valid_mask(gw + 2) >> lane) & 1ULL) && (pre == 0ULL);
        u64 cm = mc[2][2];
        u64 K = __ballot(alive0);
        for (int it = 0; it < 70; ++it) {
          bool alive = alive0 && ((K & cm) == 0ULL);
          u64 Kn = __ballot(alive);
          if (Kn == K) break;
          K = Kn;
        }
        K2 = K;
      }
      {
        u64 pre = (K0 & mc[3][0]) | (K1 & mc[3][1]) | (K2 & mc[3][2]);
        bool alive0 = (f3 == 0u) && ((valid_mask(gw + 3) >> lane) & 1ULL) && (pre == 0ULL);
        u64 cm = mc[3][3];
        u64 K = __ballot(alive0);
        for (int it = 0; it < 70; ++it) {
          bool alive = alive0 && ((K & cm) == 0ULL);
          u64 Kn = __ballot(alive);
          if (Kn == K) break;
          K = Kn;
        }
        K3 = K;
      }
      if (lane == 0) {
        Kall[gw] = K0;
        Kall[gw + 1] = K1;
        Kall[gw + 2] = K2;
        Kall[gw + 3] = K3;
        baseT[t] = total;
      }
      total += __popcll(K0) + __popcll(K1) + __popcll(K2) + __popcll(K3);
#pragma unroll
      for (int q = 0; q < 4; ++q)
#pragma unroll
        for (int j = 0; j < 4; ++j)
          mc[q][j] = mn[q][j];
    }
  }
  __syncthreads();
  for (int i = tid; i < NSEL; i += 512) {
    int g = i >> 6, bb = i & 63;
    u64 K = Kall[g];
    if ((K >> bb) & 1ULL) {
      int t = i >> 8;
      int rank = baseT[t];
      for (int q = t * 4; q < g; ++q) rank += __popcll(Kall[q]);
      rank += __popcll(K & ((1ULL << bb) - 1ULL));
      if (rank < PROP) out[(size_t)b * PROP + rank] = boxes[(size_t)b * NPAD + i];
    }
  }
}

extern "C" void kernel_launch(void* const* d_in, const int* in_sizes, int n_in,
                              void* d_out, int out_size, void* d_ws, size_t ws_size,
                              hipStream_t stream) {
  const float* probs = (const float*)d_in[0];    // (8,131072,2)
  const float* deltas = (const float*)d_in[1];   // (8,131072,4)
  const float* anchors = (const float*)d_in[2];  // (8,131072,4)
  char* ws = (char*)d_ws;
  int* histPB = (int*)(ws + OFF_HISTPB);
  int* bfill = (int*)(ws + OFF_BFILL);
  int* scnt = (int*)(ws + OFF_SCNT);
  int* cellCnt = (int*)(ws + OFF_CELLCNT);
  u64* tileT = (u64*)(ws + OFF_TILET);
  u64* cand = (u64*)(ws + OFF_CAND);
  float4* boxes = (float4*)(ws + OFF_BOXES);
  u16* cellList = (u16*)(ws + OFF_CELLLIST);
  u16* largeList = (u16*)(ws + OFF_LARGE);
  u32* sent = (u32*)(ws + OFF_SENT);

  hist_kernel<<<dim3(HB, BATCH), 256, 0, stream>>>(probs, histPB, bfill, scnt, cellCnt);
  gather_kernel<<<dim3(64, BATCH), 256, 0, stream>>>(probs, histPB, bfill, cand);
  sortdecode_kernel<<<dim3(64, BATCH), 256, 0, stream>>>(histPB, bfill, cand, anchors,
                                                         deltas, boxes, cellCnt,
                                                         cellList, largeList, tileT);
  pairs_kernel<<<dim3(128, BATCH), 256, 0, stream>>>(boxes, cellList, largeList,
                                                     cellCnt, tileT, sent, scnt);
  nms_kernel<<<BATCH, 512, 0, stream>>>(sent, scnt, tileT, boxes, (float4*)d_out);
}